// Round 2
// baseline (518.910 us; speedup 1.0000x reference)
//
#include <hip/hip_runtime.h>
#include <hip/hip_bf16.h>
#include <hip/hip_fp16.h>

#define DIMK 1024
#define SEQ  2048
#define BATCH 4
#define NTOK (BATCH*SEQ)                    // 8192
#define PROJ_ELEMS ((size_t)NTOK*DIMK)      // 8388608
#define LD 2048                             // leading dim (elements) of every GEMM operand

typedef unsigned short ushort_t;
typedef __attribute__((ext_vector_type(8))) short short8;   // 8 x bf16 (4 VGPRs)
typedef __attribute__((ext_vector_type(4))) float float4v;  // MFMA accumulator

#define MFMA_BF16 __builtin_amdgcn_mfma_f32_16x16x32_bf16

__device__ __forceinline__ unsigned short f2bf(float f) {
    union { float f; unsigned int i; } x; x.f = f;
    unsigned int r = x.i + 0x7fffu + ((x.i >> 16) & 1u);    // RNE
    return (unsigned short)(r >> 16);
}

// global -> LDS direct copy, 16 B per lane. LDS dest is wave-uniform base;
// HW scatters lane i to base + i*16. Source address is per-lane.
__device__ __forceinline__ void gld_lds16(const void* g, void* l) {
    auto gp = reinterpret_cast<const __attribute__((address_space(1))) unsigned int*>(
        reinterpret_cast<uintptr_t>(g));
    auto lp = reinterpret_cast<__attribute__((address_space(3))) unsigned int*>(
        reinterpret_cast<uintptr_t>(l));
    __builtin_amdgcn_global_load_lds(gp, lp, 16, 0, 0);
}

// Stage one pair of 16x32 sub-chunk units (rg0, rg0+1): 2 global_load_lds per
// thread. Source swizzle (verified conflict-free + coalesced): within each
// 16-row unit, row g's 16B chunk c sits at slot (c + g/2) & 3 — a permutation
// inside each 64B line, so staging lanes 4g..4g+3 still cover one aligned
// 64B segment.
__device__ __forceinline__ void stage2(const ushort_t* __restrict__ gbase,
                                       ushort_t* lbase, int kcol,
                                       int rg0, int g, int scol)
{
    gld_lds16(gbase + (size_t)(rg0 * 16 + g) * LD + kcol + scol,
              lbase + rg0 * 512);
    gld_lds16(gbase + (size_t)(rg0 * 16 + 16 + g) * LD + kcol + scol,
              lbase + rg0 * 512 + 512);
}

// ---------------------------------------------------------------------------
// 256x256-tile 8-phase MFMA core with REGISTER-FRAGMENT PIPELINE (T2+T3+T4+T5):
//   C(256x256) += A(256xK) * B(256xK)^T, row-major bf16, ld=2048.
//   Block = 512 threads = 8 waves (2M x 4N); wave output = 128x64.
//   BK=64 per K-tile, double-buffered LDS (128 KiB total).
//   Each phase issues the NEXT phase's 8 ds_read_b128 into the alternate
//   register set, so the MFMA's implicit wait is a counted lgkmcnt(8) —
//   ds_read latency rides across the barrier under the previous MFMA cluster.
//   Staging: ph0 stages next tile's kh0 (B+A), ph1 stages kh1 (B+A).
//   vmcnt(4) sits AFTER the MFMA of ph0 and ph2 (before the closing barrier):
//     end ph0: drains this tile's kh1 (issued prev ph1, 3 phases ago)
//     end ph2: drains next tile's kh0 (issued this ph0)
//   Never vmcnt(0) in steady state; 4 loads always left in flight.
//   Phase -> consumption map (set0/set1 alternate):
//     ph0: MFMA set0 (kh0, A-lo -> acc[0..3]);  readahead set1 = kh0 A-hi
//     ph1: MFMA set1 (kh0, A-hi -> acc[4..7]);  readahead set0 = kh1 A-lo
//     ph2: MFMA set0 (kh1, A-lo -> acc[0..3]);  readahead set1 = kh1 A-hi
//     ph3: MFMA set1 (kh1, A-hi -> acc[4..7]);  readahead set0 = next-tile kh0 A-lo
// LDS layout per buffer (elements): [kh(2)][unit(16)][512]; unit = 16 rows x
// 32 cols with the verified intra-64B permutation.
// ---------------------------------------------------------------------------
__device__ __forceinline__ void gemm_core256(
    const ushort_t* __restrict__ Arow,   // A + m0*LD  (m0 = 256-row tile base)
    const ushort_t* __restrict__ Brow,   // B + n0*LD
    int kend,                            // multiple of 256
    ushort_t* Alds, ushort_t* Blds,      // 2*16384 elements each
    float4v acc[8][4], int wid, int lane)
{
    const int g    = lane >> 2;
    const int sx   = lane & 3;
    const int scol = ((sx - (g >> 1)) & 3) * 8;
    const int r16  = lane & 15;
    const int quad = lane >> 4;
    const int roff = r16 * 32 + ((quad + (r16 >> 1)) & 3) * 8;
    const int wm8 = (wid >> 2) * 8;      // A unit base (0 or 8)
    const int wn4 = (wid & 3) * 4;       // B unit base
    const int rg0 = wid * 2;             // this wave's 2 staging units
    const int NT = kend >> 6;

    short8 a0[4], b0[4], a1[4], b1[4];

    // prologue: tile 0 -> buffer 0 (kh0 first, then kh1)
    stage2(Brow, Blds,        0,  rg0, g, scol);
    stage2(Arow, Alds,        0,  rg0, g, scol);
    stage2(Brow, Blds + 8192, 32, rg0, g, scol);
    stage2(Arow, Alds + 8192, 32, rg0, g, scol);
    asm volatile("s_waitcnt vmcnt(4)" ::: "memory");
    __builtin_amdgcn_s_barrier();
    // set0 <- tile0 ph0 fragments (kh0, A-lo)
    #pragma unroll
    for (int j = 0; j < 4; ++j)
        b0[j] = *(const short8*)(Blds + (wn4 + j) * 512 + roff);
    #pragma unroll
    for (int i = 0; i < 4; ++i)
        a0[i] = *(const short8*)(Alds + (wm8 + i) * 512 + roff);

    for (int t = 0; t < NT; ++t) {
        const int d     = (t & 1) << 14;       // element offset of read buffer
        const int dn    = d ^ 16384;           // write buffer (tile t+1)
        const int knext = (t + 1) << 6;
        const bool pre  = (t + 1 < NT);

        // -------- ph0: MFMA set0; readahead set1 = (d, kh0, A-hi); stage kh0 --------
        #pragma unroll
        for (int j = 0; j < 4; ++j)
            b1[j] = *(const short8*)(Blds + d + (wn4 + j) * 512 + roff);
        #pragma unroll
        for (int i = 0; i < 4; ++i)
            a1[i] = *(const short8*)(Alds + d + (wm8 + 4 + i) * 512 + roff);
        if (pre) {
            stage2(Brow, Blds + dn, knext, rg0, g, scol);
            stage2(Arow, Alds + dn, knext, rg0, g, scol);
        }
        asm volatile("" ::: "memory");
        __builtin_amdgcn_s_barrier();
        __builtin_amdgcn_s_setprio(1);
        #pragma unroll
        for (int i = 0; i < 4; ++i)
            #pragma unroll
            for (int j = 0; j < 4; ++j)
                acc[i][j] = MFMA_BF16(a0[i], b0[j], acc[i][j], 0, 0, 0);
        __builtin_amdgcn_s_setprio(0);
        if (pre) asm volatile("s_waitcnt vmcnt(4)" ::: "memory");  // drain this tile's kh1
        else     asm volatile("s_waitcnt vmcnt(0)" ::: "memory");
        __builtin_amdgcn_s_barrier();

        // -------- ph1: MFMA set1; readahead set0 = (d, kh1, A-lo); stage kh1 --------
        #pragma unroll
        for (int j = 0; j < 4; ++j)
            b0[j] = *(const short8*)(Blds + d + 8192 + (wn4 + j) * 512 + roff);
        #pragma unroll
        for (int i = 0; i < 4; ++i)
            a0[i] = *(const short8*)(Alds + d + 8192 + (wm8 + i) * 512 + roff);
        if (pre) {
            stage2(Brow, Blds + dn + 8192, knext + 32, rg0, g, scol);
            stage2(Arow, Alds + dn + 8192, knext + 32, rg0, g, scol);
        }
        asm volatile("" ::: "memory");
        __builtin_amdgcn_s_barrier();
        __builtin_amdgcn_s_setprio(1);
        #pragma unroll
        for (int i = 0; i < 4; ++i)
            #pragma unroll
            for (int j = 0; j < 4; ++j)
                acc[4 + i][j] = MFMA_BF16(a1[i], b1[j], acc[4 + i][j], 0, 0, 0);
        __builtin_amdgcn_s_setprio(0);
        asm volatile("" ::: "memory");
        __builtin_amdgcn_s_barrier();

        // -------- ph2: MFMA set0; readahead set1 = (d, kh1, A-hi) --------
        #pragma unroll
        for (int j = 0; j < 4; ++j)
            b1[j] = *(const short8*)(Blds + d + 8192 + (wn4 + j) * 512 + roff);
        #pragma unroll
        for (int i = 0; i < 4; ++i)
            a1[i] = *(const short8*)(Alds + d + 8192 + (wm8 + 4 + i) * 512 + roff);
        asm volatile("" ::: "memory");
        __builtin_amdgcn_s_barrier();
        __builtin_amdgcn_s_setprio(1);
        #pragma unroll
        for (int i = 0; i < 4; ++i)
            #pragma unroll
            for (int j = 0; j < 4; ++j)
                acc[i][j] = MFMA_BF16(a0[i], b0[j], acc[i][j], 0, 0, 0);
        __builtin_amdgcn_s_setprio(0);
        if (pre) asm volatile("s_waitcnt vmcnt(4)" ::: "memory");  // drain next tile's kh0
        __builtin_amdgcn_s_barrier();

        // -------- ph3: MFMA set1; readahead set0 = (dn, kh0, A-lo) --------
        if (pre) {
            #pragma unroll
            for (int j = 0; j < 4; ++j)
                b0[j] = *(const short8*)(Blds + dn + (wn4 + j) * 512 + roff);
            #pragma unroll
            for (int i = 0; i < 4; ++i)
                a0[i] = *(const short8*)(Alds + dn + (wm8 + i) * 512 + roff);
        }
        asm volatile("" ::: "memory");
        __builtin_amdgcn_s_barrier();
        __builtin_amdgcn_s_setprio(1);
        #pragma unroll
        for (int i = 0; i < 4; ++i)
            #pragma unroll
            for (int j = 0; j < 4; ++j)
                acc[4 + i][j] = MFMA_BF16(a1[i], b1[j], acc[4 + i][j], 0, 0, 0);
        __builtin_amdgcn_s_setprio(0);
        asm volatile("" ::: "memory");
        __builtin_amdgcn_s_barrier();
    }
}

// ---------------------------------------------------------------------------
// Merged projection GEMM: [Q|K|V]cat[8192,2048] = Zcat[8192,2048] @ Wall^T,
// Wall = [Wsq;Wsk;Wsv] rows 0..6143. grid (24, 32); n-tile picks the output.
// ---------------------------------------------------------------------------
__global__ __launch_bounds__(512, 2)
void gemm_proj(const ushort_t* __restrict__ A, const ushort_t* __restrict__ B,
               ushort_t* __restrict__ Cq, ushort_t* __restrict__ Ck,
               ushort_t* __restrict__ Cv)
{
    __shared__ ushort_t smem[65536];           // 128 KiB
    const int tid = threadIdx.x, wid = tid >> 6, lane = tid & 63;
    const int m0 = blockIdx.y * 256;
    const int n0g = blockIdx.x * 256;          // 0..5888
    ushort_t* C = (n0g < 2048) ? Cq : ((n0g < 4096) ? Ck : Cv);
    const int n0 = n0g & 2047;
    float4v acc[8][4] = {};
    gemm_core256(A + (size_t)m0 * LD, B + (size_t)n0g * LD, 2048,
                 smem, smem + 32768, acc, wid, lane);

    const int wm = wid >> 2, wn = wid & 3;
    const int col16 = lane & 15, quad = lane >> 4;
    #pragma unroll
    for (int i = 0; i < 8; ++i)
        #pragma unroll
        for (int j = 0; j < 4; ++j) {
            const int n = n0 + wn * 64 + j * 16 + col16;
            #pragma unroll
            for (int r = 0; r < 4; ++r) {
                const int m = m0 + wm * 128 + i * 16 + quad * 4 + r;
                C[(size_t)m * LD + n] = f2bf(acc[i][j][r]);
            }
        }
}

// ---------------------------------------------------------------------------
// Scores GEMM (causal tiles): S[b][s][t] fp16 = (Qcat@Kcat^T)*scale
// grid (8 t-tiles, 8 s-tiles, 4 batches); skip jt>it.
// ---------------------------------------------------------------------------
__global__ __launch_bounds__(512, 2)
void gemm_scores(const ushort_t* __restrict__ Q, const ushort_t* __restrict__ K,
                 __half* __restrict__ S)
{
    const int jt = blockIdx.x, it = blockIdx.y, b = blockIdx.z;
    if (jt > it) return;
    __shared__ ushort_t smem[65536];
    const int tid = threadIdx.x, wid = tid >> 6, lane = tid & 63;
    const size_t boff = (size_t)b * SEQ * LD;
    float4v acc[8][4] = {};
    gemm_core256(Q + boff + (size_t)it * 256 * LD, K + boff + (size_t)jt * 256 * LD,
                 2048, smem, smem + 32768, acc, wid, lane);

    const int wm = wid >> 2, wn = wid & 3;
    const int col16 = lane & 15, quad = lane >> 4;
    const float scale = 0.03125f;  // 1024^-0.5
    __half* Sb = S + (size_t)b * SEQ * SEQ;
    #pragma unroll
    for (int i = 0; i < 8; ++i)
        #pragma unroll
        for (int j = 0; j < 4; ++j) {
            const int t = jt * 256 + wn * 64 + j * 16 + col16;
            #pragma unroll
            for (int r = 0; r < 4; ++r) {
                const int s = it * 256 + wm * 128 + i * 16 + quad * 4 + r;
                Sb[(size_t)s * SEQ + t] = __float2half(acc[i][j][r] * scale);
            }
        }
}

// ---------------------------------------------------------------------------
// PV GEMM: out[{r,i}][b][s][d] fp32 = P[b] @ VTstack[b]^T, K extent causal
// (P rows are zero-padded to 256 multiples by the softmax kernel).
// grid (8 n-tiles, 8 s-tiles, 4 batches). n<1024 -> real, else imag.
// ---------------------------------------------------------------------------
__global__ __launch_bounds__(512, 2)
void gemm_pv(const ushort_t* __restrict__ P, const ushort_t* __restrict__ VT,
             float* __restrict__ out)
{
    const int nt = blockIdx.x, mt = blockIdx.y, b = blockIdx.z;
    __shared__ ushort_t smem[65536];
    const int tid = threadIdx.x, wid = tid >> 6, lane = tid & 63;
    const int kend = (mt + 1) * 256;
    float4v acc[8][4] = {};
    gemm_core256(P + (size_t)b * SEQ * SEQ + (size_t)mt * 256 * LD,
                 VT + (size_t)b * LD * LD + (size_t)nt * 256 * LD,
                 kend, smem, smem + 32768, acc, wid, lane);

    const int wm = wid >> 2, wn = wid & 3;
    const int col16 = lane & 15, quad = lane >> 4;
    #pragma unroll
    for (int i = 0; i < 8; ++i)
        #pragma unroll
        for (int j = 0; j < 4; ++j) {
            const int n = nt * 256 + wn * 64 + j * 16 + col16;
            float* dst = out + ((n < 1024) ? 0 : PROJ_ELEMS);
            const int d = n & 1023;
            #pragma unroll
            for (int r = 0; r < 4; ++r) {
                const int s = mt * 256 + wm * 128 + i * 16 + quad * 4 + r;
                dst[((size_t)b * SEQ + s) * DIMK + d] = acc[i][j][r];
            }
        }
}

// ---------------------------------------------------------------------------
// Input converts
// ---------------------------------------------------------------------------
__global__ __launch_bounds__(256)
void zcat_kernel(const float* __restrict__ zr, const float* __restrict__ zi,
                 ushort_t* __restrict__ zcat)
{
    const size_t e = ((size_t)blockIdx.x * 256 + threadIdx.x) * 8;
    const size_t tok = e >> 11;
    const int c = (int)(e & 2047);
    const float* src = (c < 1024) ? (zr + tok * 1024 + c) : (zi + tok * 1024 + (c - 1024));
    float4 a = *(const float4*)src;
    float4 b = *(const float4*)(src + 4);
    ushort_t* d = zcat + e;
    d[0]=f2bf(a.x); d[1]=f2bf(a.y); d[2]=f2bf(a.z); d[3]=f2bf(a.w);
    d[4]=f2bf(b.x); d[5]=f2bf(b.y); d[6]=f2bf(b.z); d[7]=f2bf(b.w);
}

// Wstack[n][c]: n<1024: [wr[n] | -wi[n]] ; n>=1024: [wi[n-1024] | wr[n-1024]]
__global__ __launch_bounds__(256)
void wstack_kernel(const float* __restrict__ wr, const float* __restrict__ wi,
                   ushort_t* __restrict__ ws)
{
    const size_t e = ((size_t)blockIdx.x * 256 + threadIdx.x) * 8;
    const int n = (int)(e >> 11), c = (int)(e & 2047);
    const int n1 = n & 1023, c1 = c & 1023;
    const float* src;
    float sgn = 1.f;
    if (n < 1024) {
        if (c < 1024) src = wr + (size_t)n1 * 1024 + c1;
        else        { src = wi + (size_t)n1 * 1024 + c1; sgn = -1.f; }
    } else {
        src = ((c < 1024) ? wi : wr) + (size_t)n1 * 1024 + c1;
    }
    float4 a = *(const float4*)src;
    float4 b = *(const float4*)(src + 4);
    ushort_t* d = ws + e;
    d[0]=f2bf(sgn*a.x); d[1]=f2bf(sgn*a.y); d[2]=f2bf(sgn*a.z); d[3]=f2bf(sgn*a.w);
    d[4]=f2bf(sgn*b.x); d[5]=f2bf(sgn*b.y); d[6]=f2bf(sgn*b.z); d[7]=f2bf(sgn*b.w);
}

// ---------------------------------------------------------------------------
// V transpose per batch: VT[b][c][t] = Vcat[b*SEQ + t][c], 64x64 LDS tiles.
// grid (32 t-tiles, 32 c-tiles, 4 batches)
// ---------------------------------------------------------------------------
__global__ __launch_bounds__(256)
void transpose_v(const ushort_t* __restrict__ vcat, ushort_t* __restrict__ vt)
{
    __shared__ ushort_t tile[64][65];
    const int b = blockIdx.z;
    const int t0 = blockIdx.x * 64, c0 = blockIdx.y * 64;
    const int tid = threadIdx.x;
    const int r = tid >> 4, c4 = (tid & 15) * 4;
    const ushort_t* src = vcat + ((size_t)(b * SEQ + t0)) * LD + c0;
    #pragma unroll
    for (int p = 0; p < 4; ++p) {
        const int row = p * 16 + r;
        ushort4 v = *(const ushort4*)(src + (size_t)row * LD + c4);
        tile[row][c4+0]=v.x; tile[row][c4+1]=v.y; tile[row][c4+2]=v.z; tile[row][c4+3]=v.w;
    }
    __syncthreads();
    ushort_t* dst = vt + ((size_t)b * LD + c0) * LD + t0;
    #pragma unroll
    for (int p = 0; p < 4; ++p) {
        const int crow = p * 16 + r;
        ushort4 v;
        v.x = tile[c4+0][crow]; v.y = tile[c4+1][crow];
        v.z = tile[c4+2][crow]; v.w = tile[c4+3][crow];
        *(ushort4*)(dst + (size_t)crow * LD + c4) = v;
    }
}

// ---------------------------------------------------------------------------
// Causal softmax: read fp16 scores row [0,s], write bf16 P in place,
// zero-padded to a 256 multiple so the 256-tile PV consumes whole K tiles.
// ---------------------------------------------------------------------------
__global__ __launch_bounds__(256)
void softmax_kernel(__half* __restrict__ sc)
{
    const int row = blockIdx.x;          // b*SEQ + s
    const int s = row & (SEQ - 1);
    __half* x = sc + (size_t)row * SEQ;
    ushort_t* xo = (ushort_t*)x;
    const int n = s + 1;
    const int tid = threadIdx.x, wave = tid >> 6, lane = tid & 63;
    __shared__ float redm[4], reds[4];

    float m = -1e30f;
    for (int i = tid; i < n; i += 256) m = fmaxf(m, __half2float(x[i]));
    #pragma unroll
    for (int off = 32; off > 0; off >>= 1) m = fmaxf(m, __shfl_down(m, off, 64));
    if (lane == 0) redm[wave] = m;
    __syncthreads();
    if (tid == 0) redm[0] = fmaxf(fmaxf(redm[0], redm[1]), fmaxf(redm[2], redm[3]));
    __syncthreads();
    m = redm[0];

    float l = 0.f;
    for (int i = tid; i < n; i += 256) l += __expf(__half2float(x[i]) - m);
    #pragma unroll
    for (int off = 32; off > 0; off >>= 1) l += __shfl_down(l, off, 64);
    if (lane == 0) reds[wave] = l;
    __syncthreads();
    if (tid == 0) reds[0] = reds[0] + reds[1] + reds[2] + reds[3];
    __syncthreads();
    const float inv = 1.0f / reds[0];

    const int npad = min(SEQ, ((s >> 8) + 1) << 8);   // pad to 256 for PV tiles
    for (int i = tid; i < npad; i += 256) {
        float v = (i < n) ? __expf(__half2float(x[i]) - m) * inv : 0.f;
        xo[i] = f2bf(v);
    }
}

// ---------------------------------------------------------------------------
extern "C" void kernel_launch(void* const* d_in, const int* in_sizes, int n_in,
                              void* d_out, int out_size, void* d_ws, size_t ws_size,
                              hipStream_t stream)
{
    const float* z_real = (const float*)d_in[0];
    const float* z_imag = (const float*)d_in[1];
    const float* wq_r   = (const float*)d_in[2];
    const float* wq_i   = (const float*)d_in[3];
    const float* wk_r   = (const float*)d_in[4];
    const float* wk_i   = (const float*)d_in[5];
    const float* wv_r   = (const float*)d_in[6];
    const float* wv_i   = (const float*)d_in[7];
    // d_in[8]: causal tril mask, handled analytically.

    // Workspace layout (bytes), lifetimes are disjoint by stream order:
    //   [0,          33554432)  Zcat bf16     -> reused as VT bf16
    //   [33554432,   58720256)  Wstack q/k/v bf16 (3 x 8 MiB, contiguous = Wall[6144,2048])
    //   [58720256,   92274688)  Qcat bf16
    //   [92274688,  125829120)  Kcat bf16
    //   [125829120, 159383552)  Vcat bf16     -> reused as scores fp16 / P bf16
    uint8_t* ws = (uint8_t*)d_ws;
    ushort_t* zcat = (ushort_t*)(ws + 0);
    ushort_t* wall = (ushort_t*)(ws + 33554432);
    ushort_t* wsq  = wall;
    ushort_t* wsk  = (ushort_t*)(ws + 33554432 + 8388608);
    ushort_t* wsv  = (ushort_t*)(ws + 33554432 + 16777216);
    ushort_t* qcat = (ushort_t*)(ws + 58720256);
    ushort_t* kcat = (ushort_t*)(ws + 92274688);
    ushort_t* vcat = (ushort_t*)(ws + 125829120);
    ushort_t* vt   = (ushort_t*)(ws + 0);
    __half*   sc   = (__half*)(ws + 125829120);
    float*    outp = (float*)d_out;

    zcat_kernel<<<dim3(8192), dim3(256), 0, stream>>>(z_real, z_imag, zcat);
    wstack_kernel<<<dim3(2048), dim3(256), 0, stream>>>(wq_r, wq_i, wsq);
    wstack_kernel<<<dim3(2048), dim3(256), 0, stream>>>(wk_r, wk_i, wsk);
    wstack_kernel<<<dim3(2048), dim3(256), 0, stream>>>(wv_r, wv_i, wsv);

    gemm_proj<<<dim3(24, 32), dim3(512), 0, stream>>>(zcat, wall, qcat, kcat, vcat);

    transpose_v<<<dim3(32, 32, 4), dim3(256), 0, stream>>>(vcat, vt);
    gemm_scores<<<dim3(8, 8, 4), dim3(512), 0, stream>>>(qcat, kcat, sc);
    softmax_kernel<<<dim3(NTOK), dim3(256), 0, stream>>>(sc);
    gemm_pv<<<dim3(8, 8, 4), dim3(512), 0, stream>>>((ushort_t*)sc, vt, outp);
}

// Round 3
// 483.388 us; speedup vs baseline: 1.0735x; 1.0735x over previous
//
#include <hip/hip_runtime.h>
#include <hip/hip_bf16.h>
#include <hip/hip_fp16.h>

#define DIMK 1024
#define SEQ  2048
#define BATCH 4
#define NTOK (BATCH*SEQ)                    // 8192
#define PROJ_ELEMS ((size_t)NTOK*DIMK)      // 8388608
#define LD 2048                             // leading dim (elements) of every GEMM operand

typedef unsigned short ushort_t;
typedef __attribute__((ext_vector_type(8))) short short8;   // 8 x bf16 (4 VGPRs)
typedef __attribute__((ext_vector_type(4))) float float4v;  // MFMA accumulator

#define MFMA_BF16 __builtin_amdgcn_mfma_f32_16x16x32_bf16

__device__ __forceinline__ unsigned short f2bf(float f) {
    union { float f; unsigned int i; } x; x.f = f;
    unsigned int r = x.i + 0x7fffu + ((x.i >> 16) & 1u);    // RNE
    return (unsigned short)(r >> 16);
}

// global -> LDS direct copy, 16 B per lane. LDS dest is wave-uniform base;
// HW scatters lane i to base + i*16. Source address is per-lane.
__device__ __forceinline__ void gld_lds16(const void* g, void* l) {
    auto gp = reinterpret_cast<const __attribute__((address_space(1))) unsigned int*>(
        reinterpret_cast<uintptr_t>(g));
    auto lp = reinterpret_cast<__attribute__((address_space(3))) unsigned int*>(
        reinterpret_cast<uintptr_t>(l));
    __builtin_amdgcn_global_load_lds(gp, lp, 16, 0, 0);
}

// Stage one pair of 16x32 sub-chunk units (rg0, rg0+1): 2 global_load_lds per
// thread. Source swizzle (verified conflict-free + coalesced): within each
// 16-row unit, row g's 16B chunk c sits at slot (c + g/2) & 3 — a permutation
// inside each 64B line, so staging lanes 4g..4g+3 still cover one aligned
// 64B segment.
__device__ __forceinline__ void stage2(const ushort_t* __restrict__ gbase,
                                       ushort_t* lbase, int kcol,
                                       int rg0, int g, int scol)
{
    gld_lds16(gbase + (size_t)(rg0 * 16 + g) * LD + kcol + scol,
              lbase + rg0 * 512);
    gld_lds16(gbase + (size_t)(rg0 * 16 + 16 + g) * LD + kcol + scol,
              lbase + rg0 * 512 + 512);
}

// ---------------------------------------------------------------------------
// 256x256-tile 8-phase MFMA core (T2+T3+T4+T5), R1 structure:
//   C(256x256) += A(256xK) * B(256xK)^T, row-major bf16, ld=2048.
//   Block = 512 threads = 8 waves (2M x 4N); wave output = 128x64.
//   BK=64 per K-tile, double-buffered LDS (128 KiB total).
//   Per K-tile: 4 phases, each {ds_read frags || stage 2 units of tile t+1,
//   barrier, [compiler-counted lgkm waits], setprio(1), 16 MFMA, setprio(0),
//   barrier}. NOTE (R3): no explicit lgkmcnt(0) — fragments are plain C++
//   loads, so the compiler emits fine-grained lgkmcnt(N) interleaved with the
//   MFMA cluster, hiding ds_read latency under the first MFMAs (m97 disasm
//   behavior). Every read has a consuming MFMA before the closing barrier, so
//   buffer d is fully read before tile t+1 stages into it — race-free.
//   Staging for tile t+1 during tile t: ph0 B(kh0), ph1 A(kh0), ph2 B(kh1),
//   ph3 A(kh1). vmcnt(4) before the closing barriers of ph1 (drains this
//   tile's kh1) and ph3 (drains next tile's kh0); never 0 in steady state.
// LDS unit layout per buffer (elements): [kh(2)][unit(16)][512]; unit =
// 16 rows x 32 cols with the verified intra-64B permutation.
// ---------------------------------------------------------------------------
__device__ __forceinline__ void gemm_core256(
    const ushort_t* __restrict__ Arow,   // A + m0*LD  (m0 = 256-row tile base)
    const ushort_t* __restrict__ Brow,   // B + n0*LD
    int kend,                            // multiple of 256
    ushort_t* Alds, ushort_t* Blds,      // 2*16384 elements each
    float4v acc[8][4], int wid, int lane)
{
    const int g    = lane >> 2;                         // staging row in unit
    const int sx   = lane & 3;                          // staging slot in 64B line
    const int scol = ((sx - (g >> 1)) & 3) * 8;         // swizzled source chunk
    const int r16  = lane & 15;                         // fragment row
    const int quad = lane >> 4;                         // fragment k-chunk
    const int roff = r16 * 32 + ((quad + (r16 >> 1)) & 3) * 8;  // swizzled read
    const int wm8 = (wid >> 2) * 8;      // A unit base (0 or 8)
    const int wn4 = (wid & 3) * 4;       // B unit base
    const int rg0 = wid * 2;             // this wave's 2 staging units
    const int NT = kend >> 6;

    // prologue: tile 0 -> buffer 0. First 4 loads = B kh0 + A kh0 (needed at
    // ph0), last 4 = kh1.
    stage2(Brow, Blds,        0,  rg0, g, scol);   // B kh0
    stage2(Arow, Alds,        0,  rg0, g, scol);   // A kh0
    stage2(Brow, Blds + 8192, 32, rg0, g, scol);   // B kh1
    stage2(Arow, Alds + 8192, 32, rg0, g, scol);   // A kh1
    asm volatile("s_waitcnt vmcnt(4)" ::: "memory");
    __builtin_amdgcn_s_barrier();

    for (int t = 0; t < NT; ++t) {
        const int d     = (t & 1) << 14;       // element offset of read buffer
        const int dn    = d ^ 16384;           // write buffer (tile t+1)
        const int knext = (t + 1) << 6;
        const bool pre  = (t + 1 < NT);
        short8 af[4], bf[4];

        // -------- phase 0: kh=0, M-frags 0-3, stage B(kh0) --------
        #pragma unroll
        for (int j = 0; j < 4; ++j)
            bf[j] = *(const short8*)(Blds + d + (wn4 + j) * 512 + roff);
        #pragma unroll
        for (int ii = 0; ii < 4; ++ii)
            af[ii] = *(const short8*)(Alds + d + (wm8 + ii) * 512 + roff);
        if (pre) stage2(Brow, Blds + dn, knext, rg0, g, scol);
        asm volatile("" ::: "memory");
        __builtin_amdgcn_s_barrier();
        __builtin_amdgcn_s_setprio(1);
        #pragma unroll
        for (int ii = 0; ii < 4; ++ii)
            #pragma unroll
            for (int j = 0; j < 4; ++j)
                acc[ii][j] = MFMA_BF16(af[ii], bf[j], acc[ii][j], 0, 0, 0);
        __builtin_amdgcn_s_setprio(0);
        asm volatile("" ::: "memory");
        __builtin_amdgcn_s_barrier();

        // -------- phase 1: kh=0, M-frags 4-7 (B reused), stage A(kh0) --------
        #pragma unroll
        for (int ii = 0; ii < 4; ++ii)
            af[ii] = *(const short8*)(Alds + d + (wm8 + 4 + ii) * 512 + roff);
        if (pre) {
            stage2(Arow, Alds + dn, knext, rg0, g, scol);
            // guarantee: this tile's kh1 data (staged prev tile ph2/ph3) landed
            asm volatile("s_waitcnt vmcnt(4)" ::: "memory");
        } else {
            asm volatile("s_waitcnt vmcnt(0)" ::: "memory");
        }
        __builtin_amdgcn_s_barrier();
        __builtin_amdgcn_s_setprio(1);
        #pragma unroll
        for (int ii = 0; ii < 4; ++ii)
            #pragma unroll
            for (int j = 0; j < 4; ++j)
                acc[4 + ii][j] = MFMA_BF16(af[ii], bf[j], acc[4 + ii][j], 0, 0, 0);
        __builtin_amdgcn_s_setprio(0);
        asm volatile("" ::: "memory");
        __builtin_amdgcn_s_barrier();

        // -------- phase 2: kh=1, M-frags 0-3, stage B(kh1) --------
        #pragma unroll
        for (int j = 0; j < 4; ++j)
            bf[j] = *(const short8*)(Blds + d + 8192 + (wn4 + j) * 512 + roff);
        #pragma unroll
        for (int ii = 0; ii < 4; ++ii)
            af[ii] = *(const short8*)(Alds + d + 8192 + (wm8 + ii) * 512 + roff);
        if (pre) stage2(Brow, Blds + dn + 8192, knext + 32, rg0, g, scol);
        asm volatile("" ::: "memory");
        __builtin_amdgcn_s_barrier();
        __builtin_amdgcn_s_setprio(1);
        #pragma unroll
        for (int ii = 0; ii < 4; ++ii)
            #pragma unroll
            for (int j = 0; j < 4; ++j)
                acc[ii][j] = MFMA_BF16(af[ii], bf[j], acc[ii][j], 0, 0, 0);
        __builtin_amdgcn_s_setprio(0);
        asm volatile("" ::: "memory");
        __builtin_amdgcn_s_barrier();

        // -------- phase 3: kh=1, M-frags 4-7 (B reused), stage A(kh1) --------
        #pragma unroll
        for (int ii = 0; ii < 4; ++ii)
            af[ii] = *(const short8*)(Alds + d + 8192 + (wm8 + 4 + ii) * 512 + roff);
        if (pre) {
            stage2(Arow, Alds + dn + 8192, knext + 32, rg0, g, scol);
            // tile boundary: guarantee tile t+1's kh0 data (staged ph0/ph1) landed
            asm volatile("s_waitcnt vmcnt(4)" ::: "memory");
        } else {
            asm volatile("" ::: "memory");
        }
        __builtin_amdgcn_s_barrier();
        __builtin_amdgcn_s_setprio(1);
        #pragma unroll
        for (int ii = 0; ii < 4; ++ii)
            #pragma unroll
            for (int j = 0; j < 4; ++j)
                acc[4 + ii][j] = MFMA_BF16(af[ii], bf[j], acc[4 + ii][j], 0, 0, 0);
        __builtin_amdgcn_s_setprio(0);
        asm volatile("" ::: "memory");
        __builtin_amdgcn_s_barrier();
    }
}

// ---------------------------------------------------------------------------
// Merged projection GEMM: [Q|K|V]cat[8192,2048] = Zcat[8192,2048] @ Wall^T,
// Wall = [Wsq;Wsk;Wsv] rows 0..6143. grid (24, 32); n-tile picks the output.
// ---------------------------------------------------------------------------
__global__ __launch_bounds__(512, 2)
void gemm_proj(const ushort_t* __restrict__ A, const ushort_t* __restrict__ B,
               ushort_t* __restrict__ Cq, ushort_t* __restrict__ Ck,
               ushort_t* __restrict__ Cv)
{
    __shared__ ushort_t smem[65536];           // 128 KiB
    const int tid = threadIdx.x, wid = tid >> 6, lane = tid & 63;
    const int m0 = blockIdx.y * 256;
    const int n0g = blockIdx.x * 256;          // 0..5888
    ushort_t* C = (n0g < 2048) ? Cq : ((n0g < 4096) ? Ck : Cv);
    const int n0 = n0g & 2047;
    float4v acc[8][4] = {};
    gemm_core256(A + (size_t)m0 * LD, B + (size_t)n0g * LD, 2048,
                 smem, smem + 32768, acc, wid, lane);

    const int wm = wid >> 2, wn = wid & 3;
    const int col16 = lane & 15, quad = lane >> 4;
    #pragma unroll
    for (int i = 0; i < 8; ++i)
        #pragma unroll
        for (int j = 0; j < 4; ++j) {
            const int n = n0 + wn * 64 + j * 16 + col16;
            #pragma unroll
            for (int r = 0; r < 4; ++r) {
                const int m = m0 + wm * 128 + i * 16 + quad * 4 + r;
                C[(size_t)m * LD + n] = f2bf(acc[i][j][r]);
            }
        }
}

// ---------------------------------------------------------------------------
// Scores GEMM (causal tiles): S[b][s][t] fp16 = (Qcat@Kcat^T)*scale
// grid (8 t-tiles, 8 s-tiles, 4 batches); skip jt>it.
// ---------------------------------------------------------------------------
__global__ __launch_bounds__(512, 2)
void gemm_scores(const ushort_t* __restrict__ Q, const ushort_t* __restrict__ K,
                 __half* __restrict__ S)
{
    const int jt = blockIdx.x, it = blockIdx.y, b = blockIdx.z;
    if (jt > it) return;
    __shared__ ushort_t smem[65536];
    const int tid = threadIdx.x, wid = tid >> 6, lane = tid & 63;
    const size_t boff = (size_t)b * SEQ * LD;
    float4v acc[8][4] = {};
    gemm_core256(Q + boff + (size_t)it * 256 * LD, K + boff + (size_t)jt * 256 * LD,
                 2048, smem, smem + 32768, acc, wid, lane);

    const int wm = wid >> 2, wn = wid & 3;
    const int col16 = lane & 15, quad = lane >> 4;
    const float scale = 0.03125f;  // 1024^-0.5
    __half* Sb = S + (size_t)b * SEQ * SEQ;
    #pragma unroll
    for (int i = 0; i < 8; ++i)
        #pragma unroll
        for (int j = 0; j < 4; ++j) {
            const int t = jt * 256 + wn * 64 + j * 16 + col16;
            #pragma unroll
            for (int r = 0; r < 4; ++r) {
                const int s = it * 256 + wm * 128 + i * 16 + quad * 4 + r;
                Sb[(size_t)s * SEQ + t] = __float2half(acc[i][j][r] * scale);
            }
        }
}

// ---------------------------------------------------------------------------
// PV GEMM: out[{r,i}][b][s][d] fp32 = P[b] @ VTstack[b]^T, K extent causal
// (P rows are zero-padded to 256 multiples by the softmax kernel).
// grid (8 n-tiles, 8 s-tiles, 4 batches). n<1024 -> real, else imag.
// ---------------------------------------------------------------------------
__global__ __launch_bounds__(512, 2)
void gemm_pv(const ushort_t* __restrict__ P, const ushort_t* __restrict__ VT,
             float* __restrict__ out)
{
    const int nt = blockIdx.x, mt = blockIdx.y, b = blockIdx.z;
    __shared__ ushort_t smem[65536];
    const int tid = threadIdx.x, wid = tid >> 6, lane = tid & 63;
    const int kend = (mt + 1) * 256;
    float4v acc[8][4] = {};
    gemm_core256(P + (size_t)b * SEQ * SEQ + (size_t)mt * 256 * LD,
                 VT + (size_t)b * LD * LD + (size_t)nt * 256 * LD,
                 kend, smem, smem + 32768, acc, wid, lane);

    const int wm = wid >> 2, wn = wid & 3;
    const int col16 = lane & 15, quad = lane >> 4;
    #pragma unroll
    for (int i = 0; i < 8; ++i)
        #pragma unroll
        for (int j = 0; j < 4; ++j) {
            const int n = nt * 256 + wn * 64 + j * 16 + col16;
            float* dst = out + ((n < 1024) ? 0 : PROJ_ELEMS);
            const int d = n & 1023;
            #pragma unroll
            for (int r = 0; r < 4; ++r) {
                const int s = mt * 256 + wm * 128 + i * 16 + quad * 4 + r;
                dst[((size_t)b * SEQ + s) * DIMK + d] = acc[i][j][r];
            }
        }
}

// ---------------------------------------------------------------------------
// Input converts
// ---------------------------------------------------------------------------
__global__ __launch_bounds__(256)
void zcat_kernel(const float* __restrict__ zr, const float* __restrict__ zi,
                 ushort_t* __restrict__ zcat)
{
    const size_t e = ((size_t)blockIdx.x * 256 + threadIdx.x) * 8;
    const size_t tok = e >> 11;
    const int c = (int)(e & 2047);
    const float* src = (c < 1024) ? (zr + tok * 1024 + c) : (zi + tok * 1024 + (c - 1024));
    float4 a = *(const float4*)src;
    float4 b = *(const float4*)(src + 4);
    ushort_t* d = zcat + e;
    d[0]=f2bf(a.x); d[1]=f2bf(a.y); d[2]=f2bf(a.z); d[3]=f2bf(a.w);
    d[4]=f2bf(b.x); d[5]=f2bf(b.y); d[6]=f2bf(b.z); d[7]=f2bf(b.w);
}

// Wstack[n][c]: n<1024: [wr[n] | -wi[n]] ; n>=1024: [wi[n-1024] | wr[n-1024]]
__global__ __launch_bounds__(256)
void wstack_kernel(const float* __restrict__ wr, const float* __restrict__ wi,
                   ushort_t* __restrict__ ws)
{
    const size_t e = ((size_t)blockIdx.x * 256 + threadIdx.x) * 8;
    const int n = (int)(e >> 11), c = (int)(e & 2047);
    const int n1 = n & 1023, c1 = c & 1023;
    const float* src;
    float sgn = 1.f;
    if (n < 1024) {
        if (c < 1024) src = wr + (size_t)n1 * 1024 + c1;
        else        { src = wi + (size_t)n1 * 1024 + c1; sgn = -1.f; }
    } else {
        src = ((c < 1024) ? wi : wr) + (size_t)n1 * 1024 + c1;
    }
    float4 a = *(const float4*)src;
    float4 b = *(const float4*)(src + 4);
    ushort_t* d = ws + e;
    d[0]=f2bf(sgn*a.x); d[1]=f2bf(sgn*a.y); d[2]=f2bf(sgn*a.z); d[3]=f2bf(sgn*a.w);
    d[4]=f2bf(sgn*b.x); d[5]=f2bf(sgn*b.y); d[6]=f2bf(sgn*b.z); d[7]=f2bf(sgn*b.w);
}

// ---------------------------------------------------------------------------
// V transpose per batch: VT[b][c][t] = Vcat[b*SEQ + t][c], 64x64 LDS tiles.
// grid (32 t-tiles, 32 c-tiles, 4 batches)
// ---------------------------------------------------------------------------
__global__ __launch_bounds__(256)
void transpose_v(const ushort_t* __restrict__ vcat, ushort_t* __restrict__ vt)
{
    __shared__ ushort_t tile[64][65];
    const int b = blockIdx.z;
    const int t0 = blockIdx.x * 64, c0 = blockIdx.y * 64;
    const int tid = threadIdx.x;
    const int r = tid >> 4, c4 = (tid & 15) * 4;
    const ushort_t* src = vcat + ((size_t)(b * SEQ + t0)) * LD + c0;
    #pragma unroll
    for (int p = 0; p < 4; ++p) {
        const int row = p * 16 + r;
        ushort4 v = *(const ushort4*)(src + (size_t)row * LD + c4);
        tile[row][c4+0]=v.x; tile[row][c4+1]=v.y; tile[row][c4+2]=v.z; tile[row][c4+3]=v.w;
    }
    __syncthreads();
    ushort_t* dst = vt + ((size_t)b * LD + c0) * LD + t0;
    #pragma unroll
    for (int p = 0; p < 4; ++p) {
        const int crow = p * 16 + r;
        ushort4 v;
        v.x = tile[c4+0][crow]; v.y = tile[c4+1][crow];
        v.z = tile[c4+2][crow]; v.w = tile[c4+3][crow];
        *(ushort4*)(dst + (size_t)crow * LD + c4) = v;
    }
}

// ---------------------------------------------------------------------------
// Causal softmax: read fp16 scores row [0,s], write bf16 P in place,
// zero-padded to a 256 multiple so the 256-tile PV consumes whole K tiles.
// ---------------------------------------------------------------------------
__global__ __launch_bounds__(256)
void softmax_kernel(__half* __restrict__ sc)
{
    const int row = blockIdx.x;          // b*SEQ + s
    const int s = row & (SEQ - 1);
    __half* x = sc + (size_t)row * SEQ;
    ushort_t* xo = (ushort_t*)x;
    const int n = s + 1;
    const int tid = threadIdx.x, wave = tid >> 6, lane = tid & 63;
    __shared__ float redm[4], reds[4];

    float m = -1e30f;
    for (int i = tid; i < n; i += 256) m = fmaxf(m, __half2float(x[i]));
    #pragma unroll
    for (int off = 32; off > 0; off >>= 1) m = fmaxf(m, __shfl_down(m, off, 64));
    if (lane == 0) redm[wave] = m;
    __syncthreads();
    if (tid == 0) redm[0] = fmaxf(fmaxf(redm[0], redm[1]), fmaxf(redm[2], redm[3]));
    __syncthreads();
    m = redm[0];

    float l = 0.f;
    for (int i = tid; i < n; i += 256) l += __expf(__half2float(x[i]) - m);
    #pragma unroll
    for (int off = 32; off > 0; off >>= 1) l += __shfl_down(l, off, 64);
    if (lane == 0) reds[wave] = l;
    __syncthreads();
    if (tid == 0) reds[0] = reds[0] + reds[1] + reds[2] + reds[3];
    __syncthreads();
    const float inv = 1.0f / reds[0];

    const int npad = min(SEQ, ((s >> 8) + 1) << 8);   // pad to 256 for PV tiles
    for (int i = tid; i < npad; i += 256) {
        float v = (i < n) ? __expf(__half2float(x[i]) - m) * inv : 0.f;
        xo[i] = f2bf(v);
    }
}

// ---------------------------------------------------------------------------
extern "C" void kernel_launch(void* const* d_in, const int* in_sizes, int n_in,
                              void* d_out, int out_size, void* d_ws, size_t ws_size,
                              hipStream_t stream)
{
    const float* z_real = (const float*)d_in[0];
    const float* z_imag = (const float*)d_in[1];
    const float* wq_r   = (const float*)d_in[2];
    const float* wq_i   = (const float*)d_in[3];
    const float* wk_r   = (const float*)d_in[4];
    const float* wk_i   = (const float*)d_in[5];
    const float* wv_r   = (const float*)d_in[6];
    const float* wv_i   = (const float*)d_in[7];
    // d_in[8]: causal tril mask, handled analytically.

    // Workspace layout (bytes), lifetimes are disjoint by stream order:
    //   [0,          33554432)  Zcat bf16     -> reused as VT bf16
    //   [33554432,   58720256)  Wstack q/k/v bf16 (3 x 8 MiB, contiguous = Wall[6144,2048])
    //   [58720256,   92274688)  Qcat bf16
    //   [92274688,  125829120)  Kcat bf16
    //   [125829120, 159383552)  Vcat bf16     -> reused as scores fp16 / P bf16
    uint8_t* ws = (uint8_t*)d_ws;
    ushort_t* zcat = (ushort_t*)(ws + 0);
    ushort_t* wall = (ushort_t*)(ws + 33554432);
    ushort_t* wsq  = wall;
    ushort_t* wsk  = (ushort_t*)(ws + 33554432 + 8388608);
    ushort_t* wsv  = (ushort_t*)(ws + 33554432 + 16777216);
    ushort_t* qcat = (ushort_t*)(ws + 58720256);
    ushort_t* kcat = (ushort_t*)(ws + 92274688);
    ushort_t* vcat = (ushort_t*)(ws + 125829120);
    ushort_t* vt   = (ushort_t*)(ws + 0);
    __half*   sc   = (__half*)(ws + 125829120);
    float*    outp = (float*)d_out;

    zcat_kernel<<<dim3(8192), dim3(256), 0, stream>>>(z_real, z_imag, zcat);
    wstack_kernel<<<dim3(2048), dim3(256), 0, stream>>>(wq_r, wq_i, wsq);
    wstack_kernel<<<dim3(2048), dim3(256), 0, stream>>>(wk_r, wk_i, wsk);
    wstack_kernel<<<dim3(2048), dim3(256), 0, stream>>>(wv_r, wv_i, wsv);

    gemm_proj<<<dim3(24, 32), dim3(512), 0, stream>>>(zcat, wall, qcat, kcat, vcat);

    transpose_v<<<dim3(32, 32, 4), dim3(256), 0, stream>>>(vcat, vt);
    gemm_scores<<<dim3(8, 8, 4), dim3(512), 0, stream>>>(qcat, kcat, sc);
    softmax_kernel<<<dim3(NTOK), dim3(256), 0, stream>>>(sc);
    gemm_pv<<<dim3(8, 8, 4), dim3(512), 0, stream>>>((ushort_t*)sc, vt, outp);
}

// Round 4
// 472.976 us; speedup vs baseline: 1.0971x; 1.0220x over previous
//
#include <hip/hip_runtime.h>
#include <hip/hip_bf16.h>
#include <hip/hip_fp16.h>

#define DIMK 1024
#define SEQ  2048
#define BATCH 4
#define NTOK (BATCH*SEQ)                    // 8192
#define PROJ_ELEMS ((size_t)NTOK*DIMK)      // 8388608
#define LD 2048                             // leading dim (elements) of every GEMM operand

typedef unsigned short ushort_t;
typedef __attribute__((ext_vector_type(8))) short short8;   // 8 x bf16 (4 VGPRs)
typedef __attribute__((ext_vector_type(4))) float float4v;  // MFMA accumulator

#define MFMA_BF16 __builtin_amdgcn_mfma_f32_16x16x32_bf16

__device__ __forceinline__ unsigned short f2bf(float f) {
    union { float f; unsigned int i; } x; x.f = f;
    unsigned int r = x.i + 0x7fffu + ((x.i >> 16) & 1u);    // RNE
    return (unsigned short)(r >> 16);
}

// global -> LDS direct copy, 16 B per lane. LDS dest is wave-uniform base;
// HW scatters lane i to base + i*16. Source address is per-lane.
__device__ __forceinline__ void gld_lds16(const void* g, void* l) {
    auto gp = reinterpret_cast<const __attribute__((address_space(1))) unsigned int*>(
        reinterpret_cast<uintptr_t>(g));
    auto lp = reinterpret_cast<__attribute__((address_space(3))) unsigned int*>(
        reinterpret_cast<uintptr_t>(l));
    __builtin_amdgcn_global_load_lds(gp, lp, 16, 0, 0);
}

// Stage one pair of 16x32 sub-chunk units (rg0, rg0+1): 2 global_load_lds per
// thread. Source swizzle (verified conflict-free + coalesced): within each
// 16-row unit, row g's 16B chunk c sits at slot (c + g/2) & 3 — a permutation
// inside each 64B line, so staging lanes 4g..4g+3 still cover one aligned
// 64B segment.
__device__ __forceinline__ void stage2(const ushort_t* __restrict__ gbase,
                                       ushort_t* lbase, int kcol,
                                       int rg0, int g, int scol)
{
    gld_lds16(gbase + (size_t)(rg0 * 16 + g) * LD + kcol + scol,
              lbase + rg0 * 512);
    gld_lds16(gbase + (size_t)(rg0 * 16 + 16 + g) * LD + kcol + scol,
              lbase + rg0 * 512 + 512);
}

// ---------------------------------------------------------------------------
// 256x256-tile MFMA core, TWO barriers per K-tile (R4):
//   C(256x256) += A(256xK) * B(256xK)^T, row-major bf16, ld=2048.
//   Block = 512 threads = 8 waves (2M x 4N); wave output = 128x64.
//   BK=64 per K-tile, double-buffered LDS (128 KiB total).
//   R3 post-mortem: per-phase pre-MFMA barriers serialized the LDS pipe
//   (per-CU, ~585 cyc/64KB) against the MFMA pipe (per-SIMD, 621 cyc/phase)
//   -> 52% util. This version keeps barriers ONLY at half-tile boundaries
//   (after the vmcnt waits), so the 2 waves/SIMD de-phase within a half and
//   one wave's MFMA cluster overlaps the other's ds_reads.
//   Safety: every ds_read is consumed by an MFMA before its wave reaches the
//   next barrier (dataflow), so when all waves pass a boundary barrier, all
//   reads of the buffer about to be overwritten have retired. Staging
//   visibility is carried by the counted vmcnt + barrier:
//     half0 stages next tile's kh0 (B then A, 4 loads);
//     half1 stages next tile's kh1 (B then A, 4 loads);
//     end-half0: vmcnt(4) drains prev tile's half1 stages = THIS tile's kh1;
//     end-half1: vmcnt(4) drains this tile's half0 stages = NEXT tile's kh0.
//   Never vmcnt(0) in steady state; 4 loads always in flight.
// LDS unit layout per buffer (elements): [kh(2)][unit(16)][512]; unit =
// 16 rows x 32 cols with the verified intra-64B permutation.
// ---------------------------------------------------------------------------
__device__ __forceinline__ void gemm_core256(
    const ushort_t* __restrict__ Arow,   // A + m0*LD  (m0 = 256-row tile base)
    const ushort_t* __restrict__ Brow,   // B + n0*LD
    int kend,                            // multiple of 256
    ushort_t* Alds, ushort_t* Blds,      // 2*16384 elements each
    float4v acc[8][4], int wid, int lane)
{
    const int g    = lane >> 2;                         // staging row in unit
    const int sx   = lane & 3;                          // staging slot in 64B line
    const int scol = ((sx - (g >> 1)) & 3) * 8;         // swizzled source chunk
    const int r16  = lane & 15;                         // fragment row
    const int quad = lane >> 4;                         // fragment k-chunk
    const int roff = r16 * 32 + ((quad + (r16 >> 1)) & 3) * 8;  // swizzled read
    const int wm8 = (wid >> 2) * 8;      // A unit base (0 or 8)
    const int wn4 = (wid & 3) * 4;       // B unit base
    const int rg0 = wid * 2;             // this wave's 2 staging units
    const int NT = kend >> 6;

    // prologue: tile 0 -> buffer 0. First 4 loads = B kh0 + A kh0 (needed by
    // half0), last 4 = kh1 (left in flight across the barrier).
    stage2(Brow, Blds,        0,  rg0, g, scol);   // B kh0
    stage2(Arow, Alds,        0,  rg0, g, scol);   // A kh0
    stage2(Brow, Blds + 8192, 32, rg0, g, scol);   // B kh1
    stage2(Arow, Alds + 8192, 32, rg0, g, scol);   // A kh1
    asm volatile("s_waitcnt vmcnt(4)" ::: "memory");
    __builtin_amdgcn_s_barrier();

    for (int t = 0; t < NT; ++t) {
        const int d     = (t & 1) << 14;       // element offset of read buffer
        const int dn    = d ^ 16384;           // write buffer (tile t+1)
        const int knext = (t + 1) << 6;
        const bool pre  = (t + 1 < NT);
        short8 af0[4], af1[4], bf[4];

        // ================= half 0 (kh0): 32 MFMA, stage B+A kh0 =================
        #pragma unroll
        for (int j = 0; j < 4; ++j)
            bf[j] = *(const short8*)(Blds + d + (wn4 + j) * 512 + roff);
        #pragma unroll
        for (int i = 0; i < 4; ++i)
            af0[i] = *(const short8*)(Alds + d + (wm8 + i) * 512 + roff);
        #pragma unroll
        for (int i = 0; i < 4; ++i)
            af1[i] = *(const short8*)(Alds + d + (wm8 + 4 + i) * 512 + roff);
        if (pre) {
            stage2(Brow, Blds + dn, knext, rg0, g, scol);
            stage2(Arow, Alds + dn, knext, rg0, g, scol);
        }
        __builtin_amdgcn_s_setprio(1);
        #pragma unroll
        for (int i = 0; i < 4; ++i)
            #pragma unroll
            for (int j = 0; j < 4; ++j)
                acc[i][j] = MFMA_BF16(af0[i], bf[j], acc[i][j], 0, 0, 0);
        #pragma unroll
        for (int i = 0; i < 4; ++i)
            #pragma unroll
            for (int j = 0; j < 4; ++j)
                acc[4 + i][j] = MFMA_BF16(af1[i], bf[j], acc[4 + i][j], 0, 0, 0);
        __builtin_amdgcn_s_setprio(0);
        if (pre) asm volatile("s_waitcnt vmcnt(4)" ::: "memory"); // this tile's kh1 landed
        else     asm volatile("s_waitcnt vmcnt(0)" ::: "memory");
        __builtin_amdgcn_s_barrier();

        // ================= half 1 (kh1): 32 MFMA, stage B+A kh1 =================
        #pragma unroll
        for (int j = 0; j < 4; ++j)
            bf[j] = *(const short8*)(Blds + d + 8192 + (wn4 + j) * 512 + roff);
        #pragma unroll
        for (int i = 0; i < 4; ++i)
            af0[i] = *(const short8*)(Alds + d + 8192 + (wm8 + i) * 512 + roff);
        #pragma unroll
        for (int i = 0; i < 4; ++i)
            af1[i] = *(const short8*)(Alds + d + 8192 + (wm8 + 4 + i) * 512 + roff);
        if (pre) {
            stage2(Brow, Blds + dn + 8192, knext + 32, rg0, g, scol);
            stage2(Arow, Alds + dn + 8192, knext + 32, rg0, g, scol);
        }
        __builtin_amdgcn_s_setprio(1);
        #pragma unroll
        for (int i = 0; i < 4; ++i)
            #pragma unroll
            for (int j = 0; j < 4; ++j)
                acc[i][j] = MFMA_BF16(af0[i], bf[j], acc[i][j], 0, 0, 0);
        #pragma unroll
        for (int i = 0; i < 4; ++i)
            #pragma unroll
            for (int j = 0; j < 4; ++j)
                acc[4 + i][j] = MFMA_BF16(af1[i], bf[j], acc[4 + i][j], 0, 0, 0);
        __builtin_amdgcn_s_setprio(0);
        if (pre) asm volatile("s_waitcnt vmcnt(4)" ::: "memory"); // next tile's kh0 landed
        __builtin_amdgcn_s_barrier();
    }
}

// ---------------------------------------------------------------------------
// Merged projection GEMM: [Q|K|V]cat[8192,2048] = Zcat[8192,2048] @ Wall^T,
// Wall = [Wsq;Wsk;Wsv] rows 0..6143. grid (24, 32); n-tile picks the output.
// ---------------------------------------------------------------------------
__global__ __launch_bounds__(512, 2)
void gemm_proj(const ushort_t* __restrict__ A, const ushort_t* __restrict__ B,
               ushort_t* __restrict__ Cq, ushort_t* __restrict__ Ck,
               ushort_t* __restrict__ Cv)
{
    __shared__ ushort_t smem[65536];           // 128 KiB
    const int tid = threadIdx.x, wid = tid >> 6, lane = tid & 63;
    const int m0 = blockIdx.y * 256;
    const int n0g = blockIdx.x * 256;          // 0..5888
    ushort_t* C = (n0g < 2048) ? Cq : ((n0g < 4096) ? Ck : Cv);
    const int n0 = n0g & 2047;
    float4v acc[8][4] = {};
    gemm_core256(A + (size_t)m0 * LD, B + (size_t)n0g * LD, 2048,
                 smem, smem + 32768, acc, wid, lane);

    const int wm = wid >> 2, wn = wid & 3;
    const int col16 = lane & 15, quad = lane >> 4;
    #pragma unroll
    for (int i = 0; i < 8; ++i)
        #pragma unroll
        for (int j = 0; j < 4; ++j) {
            const int n = n0 + wn * 64 + j * 16 + col16;
            #pragma unroll
            for (int r = 0; r < 4; ++r) {
                const int m = m0 + wm * 128 + i * 16 + quad * 4 + r;
                C[(size_t)m * LD + n] = f2bf(acc[i][j][r]);
            }
        }
}

// ---------------------------------------------------------------------------
// Scores GEMM (causal tiles): S[b][s][t] fp16 = (Qcat@Kcat^T)*scale
// grid (8 t-tiles, 8 s-tiles, 4 batches); skip jt>it.
// ---------------------------------------------------------------------------
__global__ __launch_bounds__(512, 2)
void gemm_scores(const ushort_t* __restrict__ Q, const ushort_t* __restrict__ K,
                 __half* __restrict__ S)
{
    const int jt = blockIdx.x, it = blockIdx.y, b = blockIdx.z;
    if (jt > it) return;
    __shared__ ushort_t smem[65536];
    const int tid = threadIdx.x, wid = tid >> 6, lane = tid & 63;
    const size_t boff = (size_t)b * SEQ * LD;
    float4v acc[8][4] = {};
    gemm_core256(Q + boff + (size_t)it * 256 * LD, K + boff + (size_t)jt * 256 * LD,
                 2048, smem, smem + 32768, acc, wid, lane);

    const int wm = wid >> 2, wn = wid & 3;
    const int col16 = lane & 15, quad = lane >> 4;
    const float scale = 0.03125f;  // 1024^-0.5
    __half* Sb = S + (size_t)b * SEQ * SEQ;
    #pragma unroll
    for (int i = 0; i < 8; ++i)
        #pragma unroll
        for (int j = 0; j < 4; ++j) {
            const int t = jt * 256 + wn * 64 + j * 16 + col16;
            #pragma unroll
            for (int r = 0; r < 4; ++r) {
                const int s = it * 256 + wm * 128 + i * 16 + quad * 4 + r;
                Sb[(size_t)s * SEQ + t] = __float2half(acc[i][j][r] * scale);
            }
        }
}

// ---------------------------------------------------------------------------
// PV GEMM: out[{r,i}][b][s][d] fp32 = P[b] @ VTstack[b]^T, K extent causal
// (P rows are zero-padded to 256 multiples by the softmax kernel).
// grid (8 n-tiles, 8 s-tiles, 4 batches). n<1024 -> real, else imag.
// ---------------------------------------------------------------------------
__global__ __launch_bounds__(512, 2)
void gemm_pv(const ushort_t* __restrict__ P, const ushort_t* __restrict__ VT,
             float* __restrict__ out)
{
    const int nt = blockIdx.x, mt = blockIdx.y, b = blockIdx.z;
    __shared__ ushort_t smem[65536];
    const int tid = threadIdx.x, wid = tid >> 6, lane = tid & 63;
    const int kend = (mt + 1) * 256;
    float4v acc[8][4] = {};
    gemm_core256(P + (size_t)b * SEQ * SEQ + (size_t)mt * 256 * LD,
                 VT + (size_t)b * LD * LD + (size_t)nt * 256 * LD,
                 kend, smem, smem + 32768, acc, wid, lane);

    const int wm = wid >> 2, wn = wid & 3;
    const int col16 = lane & 15, quad = lane >> 4;
    #pragma unroll
    for (int i = 0; i < 8; ++i)
        #pragma unroll
        for (int j = 0; j < 4; ++j) {
            const int n = nt * 256 + wn * 64 + j * 16 + col16;
            float* dst = out + ((n < 1024) ? 0 : PROJ_ELEMS);
            const int d = n & 1023;
            #pragma unroll
            for (int r = 0; r < 4; ++r) {
                const int s = mt * 256 + wm * 128 + i * 16 + quad * 4 + r;
                dst[((size_t)b * SEQ + s) * DIMK + d] = acc[i][j][r];
            }
        }
}

// ---------------------------------------------------------------------------
// Input converts
// ---------------------------------------------------------------------------
__global__ __launch_bounds__(256)
void zcat_kernel(const float* __restrict__ zr, const float* __restrict__ zi,
                 ushort_t* __restrict__ zcat)
{
    const size_t e = ((size_t)blockIdx.x * 256 + threadIdx.x) * 8;
    const size_t tok = e >> 11;
    const int c = (int)(e & 2047);
    const float* src = (c < 1024) ? (zr + tok * 1024 + c) : (zi + tok * 1024 + (c - 1024));
    float4 a = *(const float4*)src;
    float4 b = *(const float4*)(src + 4);
    ushort_t* d = zcat + e;
    d[0]=f2bf(a.x); d[1]=f2bf(a.y); d[2]=f2bf(a.z); d[3]=f2bf(a.w);
    d[4]=f2bf(b.x); d[5]=f2bf(b.y); d[6]=f2bf(b.z); d[7]=f2bf(b.w);
}

// Wstack[n][c]: n<1024: [wr[n] | -wi[n]] ; n>=1024: [wi[n-1024] | wr[n-1024]]
__global__ __launch_bounds__(256)
void wstack_kernel(const float* __restrict__ wr, const float* __restrict__ wi,
                   ushort_t* __restrict__ ws)
{
    const size_t e = ((size_t)blockIdx.x * 256 + threadIdx.x) * 8;
    const int n = (int)(e >> 11), c = (int)(e & 2047);
    const int n1 = n & 1023, c1 = c & 1023;
    const float* src;
    float sgn = 1.f;
    if (n < 1024) {
        if (c < 1024) src = wr + (size_t)n1 * 1024 + c1;
        else        { src = wi + (size_t)n1 * 1024 + c1; sgn = -1.f; }
    } else {
        src = ((c < 1024) ? wi : wr) + (size_t)n1 * 1024 + c1;
    }
    float4 a = *(const float4*)src;
    float4 b = *(const float4*)(src + 4);
    ushort_t* d = ws + e;
    d[0]=f2bf(sgn*a.x); d[1]=f2bf(sgn*a.y); d[2]=f2bf(sgn*a.z); d[3]=f2bf(sgn*a.w);
    d[4]=f2bf(sgn*b.x); d[5]=f2bf(sgn*b.y); d[6]=f2bf(sgn*b.z); d[7]=f2bf(sgn*b.w);
}

// ---------------------------------------------------------------------------
// V transpose per batch: VT[b][c][t] = Vcat[b*SEQ + t][c], 64x64 LDS tiles.
// grid (32 t-tiles, 32 c-tiles, 4 batches)
// ---------------------------------------------------------------------------
__global__ __launch_bounds__(256)
void transpose_v(const ushort_t* __restrict__ vcat, ushort_t* __restrict__ vt)
{
    __shared__ ushort_t tile[64][65];
    const int b = blockIdx.z;
    const int t0 = blockIdx.x * 64, c0 = blockIdx.y * 64;
    const int tid = threadIdx.x;
    const int r = tid >> 4, c4 = (tid & 15) * 4;
    const ushort_t* src = vcat + ((size_t)(b * SEQ + t0)) * LD + c0;
    #pragma unroll
    for (int p = 0; p < 4; ++p) {
        const int row = p * 16 + r;
        ushort4 v = *(const ushort4*)(src + (size_t)row * LD + c4);
        tile[row][c4+0]=v.x; tile[row][c4+1]=v.y; tile[row][c4+2]=v.z; tile[row][c4+3]=v.w;
    }
    __syncthreads();
    ushort_t* dst = vt + ((size_t)b * LD + c0) * LD + t0;
    #pragma unroll
    for (int p = 0; p < 4; ++p) {
        const int crow = p * 16 + r;
        ushort4 v;
        v.x = tile[c4+0][crow]; v.y = tile[c4+1][crow];
        v.z = tile[c4+2][crow]; v.w = tile[c4+3][crow];
        *(ushort4*)(dst + (size_t)crow * LD + c4) = v;
    }
}

// ---------------------------------------------------------------------------
// Causal softmax: read fp16 scores row [0,s], write bf16 P in place,
// zero-padded to a 256 multiple so the 256-tile PV consumes whole K tiles.
// ---------------------------------------------------------------------------
__global__ __launch_bounds__(256)
void softmax_kernel(__half* __restrict__ sc)
{
    const int row = blockIdx.x;          // b*SEQ + s
    const int s = row & (SEQ - 1);
    __half* x = sc + (size_t)row * SEQ;
    ushort_t* xo = (ushort_t*)x;
    const int n = s + 1;
    const int tid = threadIdx.x, wave = tid >> 6, lane = tid & 63;
    __shared__ float redm[4], reds[4];

    float m = -1e30f;
    for (int i = tid; i < n; i += 256) m = fmaxf(m, __half2float(x[i]));
    #pragma unroll
    for (int off = 32; off > 0; off >>= 1) m = fmaxf(m, __shfl_down(m, off, 64));
    if (lane == 0) redm[wave] = m;
    __syncthreads();
    if (tid == 0) redm[0] = fmaxf(fmaxf(redm[0], redm[1]), fmaxf(redm[2], redm[3]));
    __syncthreads();
    m = redm[0];

    float l = 0.f;
    for (int i = tid; i < n; i += 256) l += __expf(__half2float(x[i]) - m);
    #pragma unroll
    for (int off = 32; off > 0; off >>= 1) l += __shfl_down(l, off, 64);
    if (lane == 0) reds[wave] = l;
    __syncthreads();
    if (tid == 0) reds[0] = reds[0] + reds[1] + reds[2] + reds[3];
    __syncthreads();
    const float inv = 1.0f / reds[0];

    const int npad = min(SEQ, ((s >> 8) + 1) << 8);   // pad to 256 for PV tiles
    for (int i = tid; i < npad; i += 256) {
        float v = (i < n) ? __expf(__half2float(x[i]) - m) * inv : 0.f;
        xo[i] = f2bf(v);
    }
}

// ---------------------------------------------------------------------------
extern "C" void kernel_launch(void* const* d_in, const int* in_sizes, int n_in,
                              void* d_out, int out_size, void* d_ws, size_t ws_size,
                              hipStream_t stream)
{
    const float* z_real = (const float*)d_in[0];
    const float* z_imag = (const float*)d_in[1];
    const float* wq_r   = (const float*)d_in[2];
    const float* wq_i   = (const float*)d_in[3];
    const float* wk_r   = (const float*)d_in[4];
    const float* wk_i   = (const float*)d_in[5];
    const float* wv_r   = (const float*)d_in[6];
    const float* wv_i   = (const float*)d_in[7];
    // d_in[8]: causal tril mask, handled analytically.

    // Workspace layout (bytes), lifetimes are disjoint by stream order:
    //   [0,          33554432)  Zcat bf16     -> reused as VT bf16
    //   [33554432,   58720256)  Wstack q/k/v bf16 (3 x 8 MiB, contiguous = Wall[6144,2048])
    //   [58720256,   92274688)  Qcat bf16
    //   [92274688,  125829120)  Kcat bf16
    //   [125829120, 159383552)  Vcat bf16     -> reused as scores fp16 / P bf16
    uint8_t* ws = (uint8_t*)d_ws;
    ushort_t* zcat = (ushort_t*)(ws + 0);
    ushort_t* wall = (ushort_t*)(ws + 33554432);
    ushort_t* wsq  = wall;
    ushort_t* wsk  = (ushort_t*)(ws + 33554432 + 8388608);
    ushort_t* wsv  = (ushort_t*)(ws + 33554432 + 16777216);
    ushort_t* qcat = (ushort_t*)(ws + 58720256);
    ushort_t* kcat = (ushort_t*)(ws + 92274688);
    ushort_t* vcat = (ushort_t*)(ws + 125829120);
    ushort_t* vt   = (ushort_t*)(ws + 0);
    __half*   sc   = (__half*)(ws + 125829120);
    float*    outp = (float*)d_out;

    zcat_kernel<<<dim3(8192), dim3(256), 0, stream>>>(z_real, z_imag, zcat);
    wstack_kernel<<<dim3(2048), dim3(256), 0, stream>>>(wq_r, wq_i, wsq);
    wstack_kernel<<<dim3(2048), dim3(256), 0, stream>>>(wk_r, wk_i, wsk);
    wstack_kernel<<<dim3(2048), dim3(256), 0, stream>>>(wv_r, wv_i, wsv);

    gemm_proj<<<dim3(24, 32), dim3(512), 0, stream>>>(zcat, wall, qcat, kcat, vcat);

    transpose_v<<<dim3(32, 32, 4), dim3(256), 0, stream>>>(vcat, vt);
    gemm_scores<<<dim3(8, 8, 4), dim3(512), 0, stream>>>(qcat, kcat, sc);
    softmax_kernel<<<dim3(NTOK), dim3(256), 0, stream>>>(sc);
    gemm_pv<<<dim3(8, 8, 4), dim3(512), 0, stream>>>((ushort_t*)sc, vt, outp);
}